// Round 2
// baseline (46.068 us; speedup 1.0000x reference)
//
#include <hip/hip_runtime.h>

#ifndef NUM_CLASSES
#define NUM_CLASSES 10
#endif

// x: (B=64, TS=128, C=1, H=64, W=64) fp32 -> K = 4096
// Derivation: h_t == frame_{t-1} exactly (F_THRESH=0), so
//   out[b,c] = ( sum_k Wfc[c,k] * S[b,k] + (TS-1)*bfc[c] ) / TS,
//   S[b,k]   = sum_{t=1..TS-1} sign3(x[b,t,k] - x[b,t-1,k])
constexpr int B_       = 64;
constexpr int TS_      = 128;
constexpr int K_       = 4096;
constexpr int THREADS_ = 256;
constexpr int KV_      = 4;                       // floats per thread (float4)
constexpr int KGROUPS_ = K_ / (KV_ * THREADS_);   // 4
constexpr int TCHUNKS_ = 8;                       // 8 blocks/CU -> 32 waves/CU
constexpr int TSTEP_   = TS_ / TCHUNKS_;          // 16 diffs per chunk (last: 15)

// Kernel 1: S[tc][b][k] (int8) = sum over t-chunk of sign3(diff)
// Grid: (KGROUPS_, B_, TCHUNKS_), block: THREADS_
__global__ __launch_bounds__(THREADS_) void sign_sum_kernel(
    const float* __restrict__ x, char* __restrict__ S)
{
    const int kg = blockIdx.x;
    const int b  = blockIdx.y;
    const int tc = blockIdx.z;

    const int k0 = (kg * THREADS_ + threadIdx.x) * KV_;

    // chunk tc covers diffs t in [t_begin+1, t_end]; reads frames t_begin..t_end
    const int t_begin = tc * TSTEP_;
    const int t_end   = (tc == TCHUNKS_ - 1) ? (TS_ - 1) : (t_begin + TSTEP_);

    const float* xp = x + ((size_t)b * TS_ + t_begin) * K_ + k0;
    float4 prev = *reinterpret_cast<const float4*>(xp);

    int s0 = 0, s1 = 0, s2 = 0, s3 = 0;

#pragma unroll 4
    for (int t = t_begin + 1; t <= t_end; ++t) {
        xp += K_;
        const float4 cur = *reinterpret_cast<const float4*>(xp);
        float d;
        d = cur.x - prev.x; s0 += (d > 0.0f) - (d < 0.0f);
        d = cur.y - prev.y; s1 += (d > 0.0f) - (d < 0.0f);
        d = cur.z - prev.z; s2 += (d > 0.0f) - (d < 0.0f);
        d = cur.w - prev.w; s3 += (d > 0.0f) - (d < 0.0f);
        prev = cur;
    }

    char4* Sp = reinterpret_cast<char4*>(S + ((size_t)tc * B_ + b) * K_ + k0);
    *Sp = make_char4((char)s0, (char)s1, (char)s2, (char)s3);
}

// Kernel 2: out[b][c] = (sum_k (sum_tc S[tc][b][k]) * Wfc[c][k] + (TS-1)*bfc[c]) / TS
// Grid: B_, block: THREADS_. Fixed-order reduction -> bit-deterministic.
__global__ __launch_bounds__(THREADS_) void fc_reduce_kernel(
    const char* __restrict__ S, const float* __restrict__ Wfc,
    const float* __restrict__ bfc, float* __restrict__ out)
{
    const int b   = blockIdx.x;
    const int tid = threadIdx.x;

    float acc[NUM_CLASSES];
#pragma unroll
    for (int c = 0; c < NUM_CLASSES; ++c) acc[c] = 0.0f;

    for (int k = tid * KV_; k < K_; k += THREADS_ * KV_) {
        int sx = 0, sy = 0, sz = 0, sw = 0;
#pragma unroll
        for (int tc = 0; tc < TCHUNKS_; ++tc) {
            const char4 a = *reinterpret_cast<const char4*>(
                S + ((size_t)tc * B_ + b) * K_ + k);
            sx += a.x; sy += a.y; sz += a.z; sw += a.w;
        }
        const float fx = (float)sx, fy = (float)sy, fz = (float)sz, fw = (float)sw;
#pragma unroll
        for (int c = 0; c < NUM_CLASSES; ++c) {
            const float4 w = *reinterpret_cast<const float4*>(Wfc + (size_t)c * K_ + k);
            acc[c] += fx * w.x + fy * w.y + fz * w.z + fw * w.w;
        }
    }

    __shared__ float red[NUM_CLASSES][THREADS_];
#pragma unroll
    for (int c = 0; c < NUM_CLASSES; ++c) red[c][tid] = acc[c];
    __syncthreads();

    for (int stride = THREADS_ / 2; stride > 0; stride >>= 1) {
        if (tid < stride) {
#pragma unroll
            for (int c = 0; c < NUM_CLASSES; ++c) red[c][tid] += red[c][tid + stride];
        }
        __syncthreads();
    }

    if (tid < NUM_CLASSES) {
        out[b * NUM_CLASSES + tid] =
            (red[tid][0] + (float)(TS_ - 1) * bfc[tid]) * (1.0f / (float)TS_);
    }
}

extern "C" void kernel_launch(void* const* d_in, const int* in_sizes, int n_in,
                              void* d_out, int out_size, void* d_ws, size_t ws_size,
                              hipStream_t stream)
{
    const float* x   = (const float*)d_in[0];
    const float* Wfc = (const float*)d_in[1];
    const float* bfc = (const float*)d_in[2];
    float* out = (float*)d_out;
    char* S = (char*)d_ws;   // needs TCHUNKS_*B_*K_ = 2 MiB

    dim3 grid1(KGROUPS_, B_, TCHUNKS_);
    sign_sum_kernel<<<grid1, THREADS_, 0, stream>>>(x, S);

    fc_reduce_kernel<<<B_, THREADS_, 0, stream>>>(S, Wfc, bfc, out);
}

// Round 3
// 40.725 us; speedup vs baseline: 1.1312x; 1.1312x over previous
//
#include <hip/hip_runtime.h>

#ifndef NUM_CLASSES
#define NUM_CLASSES 10
#endif

// x: (B=64, TS=128, C=1, H=64, W=64) fp32 -> K = 4096
// Derivation: with F_THRESH=0, h_t == frame_{t-1} exactly, so
//   out[b,c] = ( sum_k Wfc[c,k] * S[b,k] + (TS-1)*bfc[c] ) / TS,
//   S[b,k]   = sum_{t=1..TS-1} sign3(x[b,t,k] - x[b,t-1,k])
// FC is fused into the streaming pass: each block reduces its k-slice's
// contribution to the 10 logits; a tiny second kernel sums 16 partials.
constexpr int B_       = 64;
constexpr int TS_      = 128;
constexpr int K_       = 4096;
constexpr int THREADS_ = 256;
constexpr int KV_      = 4;                       // floats per thread (float4)
constexpr int KGROUPS_ = K_ / (KV_ * THREADS_);   // 4
constexpr int TCHUNKS_ = 4;                       // 1024 blocks = 4/CU
constexpr int TSTEP_   = TS_ / TCHUNKS_;          // 32 diffs per chunk (last: 31)
constexpr int NPART_   = TCHUNKS_ * KGROUPS_;     // 16 partials per (b,c)

// Kernel 1: P[b][c][tc*KGROUPS+kg] = sum_{k in slice} S_chunk[b,k] * Wfc[c,k]
// Grid: (KGROUPS_, B_, TCHUNKS_), block: THREADS_
__global__ __launch_bounds__(THREADS_) void sign_fc_kernel(
    const float* __restrict__ x, const float* __restrict__ Wfc,
    float* __restrict__ P)
{
    const int kg = blockIdx.x;
    const int b  = blockIdx.y;
    const int tc = blockIdx.z;

    const int tid = threadIdx.x;
    const int k0  = (kg * THREADS_ + tid) * KV_;

    // chunk tc covers diffs t in [t_begin+1, t_end]; reads frames t_begin..t_end
    const int t_begin = tc * TSTEP_;
    const int t_end   = (tc == TCHUNKS_ - 1) ? (TS_ - 1) : (t_begin + TSTEP_);

    const float* xp = x + ((size_t)b * TS_ + t_begin) * K_ + k0;
    float4 prev = *reinterpret_cast<const float4*>(xp);

    int s0 = 0, s1 = 0, s2 = 0, s3 = 0;

#pragma unroll 4
    for (int t = t_begin + 1; t <= t_end; ++t) {
        xp += K_;
        const float4 cur = *reinterpret_cast<const float4*>(xp);
        float d;
        d = cur.x - prev.x; s0 += (d > 0.0f) - (d < 0.0f);
        d = cur.y - prev.y; s1 += (d > 0.0f) - (d < 0.0f);
        d = cur.z - prev.z; s2 += (d > 0.0f) - (d < 0.0f);
        d = cur.w - prev.w; s3 += (d > 0.0f) - (d < 0.0f);
        prev = cur;
    }

    const float fs0 = (float)s0, fs1 = (float)s1, fs2 = (float)s2, fs3 = (float)s3;

    // Per-thread FC partials over this thread's 4 k's.
    float pc[NUM_CLASSES];
#pragma unroll
    for (int c = 0; c < NUM_CLASSES; ++c) {
        const float4 w = *reinterpret_cast<const float4*>(Wfc + (size_t)c * K_ + k0);
        pc[c] = fs0 * w.x + fs1 * w.y + fs2 * w.z + fs3 * w.w;
    }

    // Fixed-order block reduction (deterministic).
    __shared__ float red[NUM_CLASSES][THREADS_];
#pragma unroll
    for (int c = 0; c < NUM_CLASSES; ++c) red[c][tid] = pc[c];
    __syncthreads();

    for (int stride = THREADS_ / 2; stride > 0; stride >>= 1) {
        if (tid < stride) {
#pragma unroll
            for (int c = 0; c < NUM_CLASSES; ++c) red[c][tid] += red[c][tid + stride];
        }
        __syncthreads();
    }

    if (tid < NUM_CLASSES) {
        P[((size_t)b * NUM_CLASSES + tid) * NPART_ + tc * KGROUPS_ + kg] = red[tid][0];
    }
}

// Kernel 2: out[b][c] = (sum_{i<16} P[b][c][i] + (TS-1)*bfc[c]) / TS
// Grid: B_, block: 64 (one wave). Fixed-order -> bit-deterministic.
__global__ __launch_bounds__(64) void fc_finish_kernel(
    const float* __restrict__ P, const float* __restrict__ bfc,
    float* __restrict__ out)
{
    const int b = blockIdx.x;
    const int c = threadIdx.x;
    if (c >= NUM_CLASSES) return;

    const float* p = P + ((size_t)b * NUM_CLASSES + c) * NPART_;
    float s = 0.0f;
#pragma unroll
    for (int i = 0; i < NPART_; ++i) s += p[i];

    out[b * NUM_CLASSES + c] = (s + (float)(TS_ - 1) * bfc[c]) * (1.0f / (float)TS_);
}

extern "C" void kernel_launch(void* const* d_in, const int* in_sizes, int n_in,
                              void* d_out, int out_size, void* d_ws, size_t ws_size,
                              hipStream_t stream)
{
    const float* x   = (const float*)d_in[0];
    const float* Wfc = (const float*)d_in[1];
    const float* bfc = (const float*)d_in[2];
    float* out = (float*)d_out;
    float* P = (float*)d_ws;   // needs B_*NUM_CLASSES*NPART_*4 = 40 KiB

    dim3 grid1(KGROUPS_, B_, TCHUNKS_);
    sign_fc_kernel<<<grid1, THREADS_, 0, stream>>>(x, Wfc, P);

    fc_finish_kernel<<<B_, 64, 0, stream>>>(P, bfc, out);
}

// Round 4
// 30.819 us; speedup vs baseline: 1.4948x; 1.3214x over previous
//
#include <hip/hip_runtime.h>

#ifndef NUM_CLASSES
#define NUM_CLASSES 10
#endif

// x: (B=64, TS=128, C=1, H=64, W=64) fp32 -> K = 4096
// Derivation: with F_THRESH=0, h_t == frame_{t-1} exactly, so
//   out[b,c] = ( sum_k Wfc[c,k] * S[b,k] + (TS-1)*bfc[c] ) / TS,
//   S[b,k]   = sum_{t=1..TS-1} sign3(x[b,t,k] - x[b,t-1,k])
// Streaming layout (R4): each block owns a CONTIGUOUS (t,k) region --
// (b, k-half, t-chunk): 8KB half-frames for consecutive t, so the block's
// HBM access stream is one unbroken ~140KB run (DRAM row-friendly), unlike
// the R1-R3 k-sliced layout (1KB read, 16KB jump -> row thrashing).
constexpr int B_        = 64;
constexpr int TS_       = 128;
constexpr int K_        = 4096;
constexpr int THREADS_  = 256;
constexpr int KHALVES_  = 2;
constexpr int KHF_      = K_ / KHALVES_;           // 2048 floats per half-frame
constexpr int TCHUNKS_  = 8;
constexpr int TSTEP_    = 16;                      // diffs per chunk (last: 15)
constexpr int NPART_    = KHALVES_ * TCHUNKS_;     // 16 partials per (b,c)

// Kernel 1: per-(b,kh,tc) block: stream frames, accumulate sign3 per k,
// then fused FC -> 10 partial logits.
// Grid: (B_, KHALVES_, TCHUNKS_) = 1024 blocks, block: 256.
__global__ __launch_bounds__(THREADS_) void sign_fc_kernel(
    const float* __restrict__ x, const float* __restrict__ Wfc,
    float* __restrict__ P)
{
    const int b   = blockIdx.x;
    const int kh  = blockIdx.y;
    const int tc  = blockIdx.z;
    const int tid = threadIdx.x;

    const int t_begin = tc * TSTEP_;
    const int t_end   = (tc == TCHUNKS_ - 1) ? (TS_ - 1) : (t_begin + TSTEP_);

    // Thread owns 8 k's: kbase + {0..3} and kbase + 1024 + {0..3}.
    const int kbase = kh * KHF_ + tid * 4;

    const float* xp = x + ((size_t)b * TS_ + t_begin) * K_ + kbase;
    float4 prev0 = *reinterpret_cast<const float4*>(xp);
    float4 prev1 = *reinterpret_cast<const float4*>(xp + 1024);

    int s0 = 0, s1 = 0, s2 = 0, s3 = 0, s4 = 0, s5 = 0, s6 = 0, s7 = 0;

#pragma unroll 4
    for (int t = t_begin + 1; t <= t_end; ++t) {
        xp += K_;
        const float4 cur0 = *reinterpret_cast<const float4*>(xp);
        const float4 cur1 = *reinterpret_cast<const float4*>(xp + 1024);
        float d;
        d = cur0.x - prev0.x; s0 += (d > 0.0f) - (d < 0.0f);
        d = cur0.y - prev0.y; s1 += (d > 0.0f) - (d < 0.0f);
        d = cur0.z - prev0.z; s2 += (d > 0.0f) - (d < 0.0f);
        d = cur0.w - prev0.w; s3 += (d > 0.0f) - (d < 0.0f);
        d = cur1.x - prev1.x; s4 += (d > 0.0f) - (d < 0.0f);
        d = cur1.y - prev1.y; s5 += (d > 0.0f) - (d < 0.0f);
        d = cur1.z - prev1.z; s6 += (d > 0.0f) - (d < 0.0f);
        d = cur1.w - prev1.w; s7 += (d > 0.0f) - (d < 0.0f);
        prev0 = cur0;
        prev1 = cur1;
    }

    const float f0 = (float)s0, f1 = (float)s1, f2 = (float)s2, f3 = (float)s3;
    const float f4 = (float)s4, f5 = (float)s5, f6 = (float)s6, f7 = (float)s7;

    // Fused FC: per-thread dot over its 8 k's. Wfc (160KB) is L2-resident.
    float acc[NUM_CLASSES];
#pragma unroll
    for (int c = 0; c < NUM_CLASSES; ++c) {
        const float* wr = Wfc + (size_t)c * K_ + kbase;
        const float4 w0 = *reinterpret_cast<const float4*>(wr);
        const float4 w1 = *reinterpret_cast<const float4*>(wr + 1024);
        acc[c] = f0 * w0.x + f1 * w0.y + f2 * w0.z + f3 * w0.w
               + f4 * w1.x + f5 * w1.y + f6 * w1.z + f7 * w1.w;
    }

    // Wave-shuffle reduce (fixed order, deterministic), then 4-wave combine.
#pragma unroll
    for (int off = 32; off > 0; off >>= 1) {
#pragma unroll
        for (int c = 0; c < NUM_CLASSES; ++c)
            acc[c] += __shfl_down(acc[c], off, 64);
    }

    __shared__ float red[NUM_CLASSES][4];
    const int wave = tid >> 6;
    const int lane = tid & 63;
    if (lane == 0) {
#pragma unroll
        for (int c = 0; c < NUM_CLASSES; ++c) red[c][wave] = acc[c];
    }
    __syncthreads();

    if (tid < NUM_CLASSES) {
        const float v = (red[tid][0] + red[tid][1]) + (red[tid][2] + red[tid][3]);
        P[((size_t)b * NUM_CLASSES + tid) * NPART_ + kh * TCHUNKS_ + tc] = v;
    }
}

// Kernel 2: out[b][c] = (sum_{i<16} P[b][c][i] + (TS-1)*bfc[c]) / TS
// Grid: B_, block: 64. Fixed-order -> bit-deterministic.
__global__ __launch_bounds__(64) void fc_finish_kernel(
    const float* __restrict__ P, const float* __restrict__ bfc,
    float* __restrict__ out)
{
    const int b = blockIdx.x;
    const int c = threadIdx.x;
    if (c >= NUM_CLASSES) return;

    const float* p = P + ((size_t)b * NUM_CLASSES + c) * NPART_;
    float s = 0.0f;
#pragma unroll
    for (int i = 0; i < NPART_; ++i) s += p[i];

    out[b * NUM_CLASSES + c] = (s + (float)(TS_ - 1) * bfc[c]) * (1.0f / (float)TS_);
}

extern "C" void kernel_launch(void* const* d_in, const int* in_sizes, int n_in,
                              void* d_out, int out_size, void* d_ws, size_t ws_size,
                              hipStream_t stream)
{
    const float* x   = (const float*)d_in[0];
    const float* Wfc = (const float*)d_in[1];
    const float* bfc = (const float*)d_in[2];
    float* out = (float*)d_out;
    float* P = (float*)d_ws;   // needs B_*NUM_CLASSES*NPART_*4 = 40 KiB

    dim3 grid1(B_, KHALVES_, TCHUNKS_);
    sign_fc_kernel<<<grid1, THREADS_, 0, stream>>>(x, Wfc, P);

    fc_finish_kernel<<<B_, 64, 0, stream>>>(P, bfc, out);
}

// Round 5
// 30.153 us; speedup vs baseline: 1.5278x; 1.0221x over previous
//
#include <hip/hip_runtime.h>

#ifndef NUM_CLASSES
#define NUM_CLASSES 10
#endif

// x: (B=64, TS=128, C=1, H=64, W=64) fp32 -> K = 4096
// Derivation: with F_THRESH=0, h_t == frame_{t-1} exactly, so
//   out[b,c] = ( sum_k Wfc[c,k] * S[b,k] + (TS-1)*bfc[c] ) / TS,
//   S[b,k]   = sum_{t=1..TS-1} sign3(x[b,t,k] - x[b,t-1,k])
// R5 layout: one block owns WHOLE frames -- block (b, tc) streams 17 full
// 16KB frames = 272KB fully contiguous (R4 still skipped every other 8KB;
// contiguity was the R4 lever: 40.7 -> 30.8us). 512-thread blocks keep
// 16 waves/CU at 512 blocks (2 blocks/CU).
constexpr int B_        = 64;
constexpr int TS_       = 128;
constexpr int K_        = 4096;
constexpr int THREADS_  = 512;
constexpr int TCHUNKS_  = 8;
constexpr int TSTEP_    = 16;                      // diffs per chunk (last: 15)
constexpr int NPART_    = TCHUNKS_;                // 8 partials per (b,c)
constexpr int NWAVES_   = THREADS_ / 64;           // 8

// Kernel 1: per-(b,tc) block: stream full frames, accumulate sign3 per k,
// fused FC -> 10 partial logits.
// Grid: (B_, TCHUNKS_) = 512 blocks, block: 512.
__global__ __launch_bounds__(THREADS_) void sign_fc_kernel(
    const float* __restrict__ x, const float* __restrict__ Wfc,
    float* __restrict__ P)
{
    const int b   = blockIdx.x;
    const int tc  = blockIdx.y;
    const int tid = threadIdx.x;

    const int t_begin = tc * TSTEP_;
    const int t_end   = (tc == TCHUNKS_ - 1) ? (TS_ - 1) : (t_begin + TSTEP_);

    // Thread owns 8 k's: tid*4 + {0..3} and 2048 + tid*4 + {0..3}.
    const int kbase = tid * 4;

    const float* xp = x + ((size_t)b * TS_ + t_begin) * K_ + kbase;
    float4 prev0 = *reinterpret_cast<const float4*>(xp);
    float4 prev1 = *reinterpret_cast<const float4*>(xp + 2048);

    int s0 = 0, s1 = 0, s2 = 0, s3 = 0, s4 = 0, s5 = 0, s6 = 0, s7 = 0;

#pragma unroll 4
    for (int t = t_begin + 1; t <= t_end; ++t) {
        xp += K_;
        const float4 cur0 = *reinterpret_cast<const float4*>(xp);
        const float4 cur1 = *reinterpret_cast<const float4*>(xp + 2048);
        float d;
        d = cur0.x - prev0.x; s0 += (d > 0.0f) - (d < 0.0f);
        d = cur0.y - prev0.y; s1 += (d > 0.0f) - (d < 0.0f);
        d = cur0.z - prev0.z; s2 += (d > 0.0f) - (d < 0.0f);
        d = cur0.w - prev0.w; s3 += (d > 0.0f) - (d < 0.0f);
        d = cur1.x - prev1.x; s4 += (d > 0.0f) - (d < 0.0f);
        d = cur1.y - prev1.y; s5 += (d > 0.0f) - (d < 0.0f);
        d = cur1.z - prev1.z; s6 += (d > 0.0f) - (d < 0.0f);
        d = cur1.w - prev1.w; s7 += (d > 0.0f) - (d < 0.0f);
        prev0 = cur0;
        prev1 = cur1;
    }

    const float f0 = (float)s0, f1 = (float)s1, f2 = (float)s2, f3 = (float)s3;
    const float f4 = (float)s4, f5 = (float)s5, f6 = (float)s6, f7 = (float)s7;

    // Fused FC: per-thread dot over its 8 k's. Wfc (160KB) is L2/L3-resident.
    float acc[NUM_CLASSES];
#pragma unroll
    for (int c = 0; c < NUM_CLASSES; ++c) {
        const float* wr = Wfc + (size_t)c * K_ + kbase;
        const float4 w0 = *reinterpret_cast<const float4*>(wr);
        const float4 w1 = *reinterpret_cast<const float4*>(wr + 2048);
        acc[c] = f0 * w0.x + f1 * w0.y + f2 * w0.z + f3 * w0.w
               + f4 * w1.x + f5 * w1.y + f6 * w1.z + f7 * w1.w;
    }

    // Wave-shuffle reduce (fixed order, deterministic), then 8-wave combine.
#pragma unroll
    for (int off = 32; off > 0; off >>= 1) {
#pragma unroll
        for (int c = 0; c < NUM_CLASSES; ++c)
            acc[c] += __shfl_down(acc[c], off, 64);
    }

    __shared__ float red[NUM_CLASSES][NWAVES_];
    const int wave = tid >> 6;
    const int lane = tid & 63;
    if (lane == 0) {
#pragma unroll
        for (int c = 0; c < NUM_CLASSES; ++c) red[c][wave] = acc[c];
    }
    __syncthreads();

    if (tid < NUM_CLASSES) {
        float v = 0.0f;
#pragma unroll
        for (int w = 0; w < NWAVES_; ++w) v += red[tid][w];
        P[((size_t)b * NUM_CLASSES + tid) * NPART_ + tc] = v;
    }
}

// Kernel 2: out[b][c] = (sum_{i<8} P[b][c][i] + (TS-1)*bfc[c]) / TS
// Grid: B_, block: 64. Fixed-order -> bit-deterministic.
__global__ __launch_bounds__(64) void fc_finish_kernel(
    const float* __restrict__ P, const float* __restrict__ bfc,
    float* __restrict__ out)
{
    const int b = blockIdx.x;
    const int c = threadIdx.x;
    if (c >= NUM_CLASSES) return;

    const float* p = P + ((size_t)b * NUM_CLASSES + c) * NPART_;
    float s = 0.0f;
#pragma unroll
    for (int i = 0; i < NPART_; ++i) s += p[i];

    out[b * NUM_CLASSES + c] = (s + (float)(TS_ - 1) * bfc[c]) * (1.0f / (float)TS_);
}

extern "C" void kernel_launch(void* const* d_in, const int* in_sizes, int n_in,
                              void* d_out, int out_size, void* d_ws, size_t ws_size,
                              hipStream_t stream)
{
    const float* x   = (const float*)d_in[0];
    const float* Wfc = (const float*)d_in[1];
    const float* bfc = (const float*)d_in[2];
    float* out = (float*)d_out;
    float* P = (float*)d_ws;   // needs B_*NUM_CLASSES*NPART_*4 = 20 KiB

    dim3 grid1(B_, TCHUNKS_);
    sign_fc_kernel<<<grid1, THREADS_, 0, stream>>>(x, Wfc, P);

    fc_finish_kernel<<<B_, 64, 0, stream>>>(P, bfc, out);
}